// Round 1
// baseline (1588.511 us; speedup 1.0000x reference)
//
#include <hip/hip_runtime.h>

typedef __attribute__((ext_vector_type(8))) short bf16x8;
typedef __attribute__((ext_vector_type(4))) float f32x4;
typedef unsigned short u16;
typedef unsigned int u32;

#define NW 49
#define NP 64
#define CDIM 384
#define NHEAD 12
#define HDIM 32
#define XS_STRIDE 392   // bf16 elems; 784 B row stride: 16B-aligned, 2-way banks
#define QK_STRIDE 40    // 80 B row stride
#define VT_STRIDE 72    // 144 B row stride
#define P_STRIDE 72
#define LDS_BYTES 159744

__device__ __forceinline__ u16 f2bf(float f) {
  u32 u = __float_as_uint(f);
  u32 r = u + 0x7fffu + ((u >> 16) & 1u);   // RNE
  return (u16)(r >> 16);
}

// prep: weights fp32->bf16, bias[h][n][m] = rpb[rel[n,m]][h]
__global__ void prep_kernel(const float* __restrict__ qkv_w,
                            const float* __restrict__ proj_w,
                            const float* __restrict__ rpb,
                            const int* __restrict__ rel,
                            u16* __restrict__ wq, u16* __restrict__ wp,
                            float* __restrict__ bias) {
  int i = blockIdx.x * 256 + threadIdx.x;
  if (i < 1152 * 384) wq[i] = f2bf(qkv_w[i]);
  if (i < 384 * 384) wp[i] = f2bf(proj_w[i]);
  if (i < 12 * 2401) {
    int h = i / 2401, nm = i % 2401;
    bias[i] = rpb[rel[nm] * 12 + h];
  }
}

__global__ __launch_bounds__(256, 1)
void wattn_kernel(const float* __restrict__ x,
                  const float* __restrict__ qkv_b,
                  const float* __restrict__ proj_b,
                  const u16* __restrict__ wq,
                  const u16* __restrict__ wp,
                  const float* __restrict__ bias,
                  float* __restrict__ out) {
  extern __shared__ u16 lds[];
  const int b = blockIdx.x;
  const int tid = threadIdx.x;
  const int wid = tid >> 6;
  const int lane = tid & 63;
  const int lr = lane & 15;   // row/col within 16 (MFMA frag)
  const int lg = lane >> 4;   // k-group 0..3

  u16* xs = lds;                          // [64][392] bf16 x tile
  u16* ao = lds + NP * XS_STRIDE;         // [64][392] attn output (pre-proj)
  u16* wb = lds + 2 * NP * XS_STRIDE + wid * 7424;  // per-wave buffers
  u16* Qb = wb;                           // [64][40]
  u16* Kb = wb + NP * QK_STRIDE;          // [64][40]
  u16* Vt = wb + 2 * NP * QK_STRIDE;      // [32][72] (V transposed)
  u16* Pb = Qb;                           // [16][72] alias (Q dead by then)

  // ---------- phase 0: stage x -> xs bf16, zero pad rows 49..63 ----------
  const float* xb = x + (size_t)b * (NW * CDIM);
  for (int i = tid; i < 15 * XS_STRIDE; i += 256) xs[49 * XS_STRIDE + i] = 0;
  for (int i = tid; i < 49 * 96; i += 256) {
    int r = i / 96, c4 = i % 96;
    float4 v = ((const float4*)xb)[i];
    ushort4 uu;
    uu.x = f2bf(v.x); uu.y = f2bf(v.y); uu.z = f2bf(v.z); uu.w = f2bf(v.w);
    *(ushort4*)&xs[r * XS_STRIDE + c4 * 4] = uu;
  }
  __syncthreads();

  const f32x4 fzero = {0.f, 0.f, 0.f, 0.f};
  const float scale = 0.17677669529663687f;  // 1/sqrt(32)

  for (int g = 0; g < 3; ++g) {
    const int h = g * 4 + wid;  // this wave's head

    // ---------- phase 1: qkv gemm for head h: M=64 N=96 K=384 ----------
    int jrow[6];
#pragma unroll
    for (int nt = 0; nt < 6; ++nt)
      jrow[nt] = (nt >> 1) * CDIM + h * HDIM + (nt & 1) * 16 + lr;

    f32x4 acc[4][6];
#pragma unroll
    for (int mt = 0; mt < 4; ++mt)
#pragma unroll
      for (int nt = 0; nt < 6; ++nt) acc[mt][nt] = fzero;

    bf16x8 aA[4], bA[6], aB[4], bB[6];
    {
      int k0 = lg * 8;
#pragma unroll
      for (int mt = 0; mt < 4; ++mt) aA[mt] = *(const bf16x8*)&xs[(mt * 16 + lr) * XS_STRIDE + k0];
#pragma unroll
      for (int nt = 0; nt < 6; ++nt) bA[nt] = *(const bf16x8*)&wq[jrow[nt] * CDIM + k0];
    }
#pragma unroll
    for (int kk = 0; kk < 6; ++kk) {
      {  // prefetch kt = 2kk+1
        int k0 = (2 * kk + 1) * 32 + lg * 8;
#pragma unroll
        for (int mt = 0; mt < 4; ++mt) aB[mt] = *(const bf16x8*)&xs[(mt * 16 + lr) * XS_STRIDE + k0];
#pragma unroll
        for (int nt = 0; nt < 6; ++nt) bB[nt] = *(const bf16x8*)&wq[jrow[nt] * CDIM + k0];
      }
#pragma unroll
      for (int nt = 0; nt < 6; ++nt)
#pragma unroll
        for (int mt = 0; mt < 4; ++mt)
          acc[mt][nt] = __builtin_amdgcn_mfma_f32_16x16x32_bf16(aA[mt], bA[nt], acc[mt][nt], 0, 0, 0);
      if (kk < 5) {  // prefetch kt = 2kk+2
        int k0 = (2 * kk + 2) * 32 + lg * 8;
#pragma unroll
        for (int mt = 0; mt < 4; ++mt) aA[mt] = *(const bf16x8*)&xs[(mt * 16 + lr) * XS_STRIDE + k0];
#pragma unroll
        for (int nt = 0; nt < 6; ++nt) bA[nt] = *(const bf16x8*)&wq[jrow[nt] * CDIM + k0];
      }
#pragma unroll
      for (int nt = 0; nt < 6; ++nt)
#pragma unroll
        for (int mt = 0; mt < 4; ++mt)
          acc[mt][nt] = __builtin_amdgcn_mfma_f32_16x16x32_bf16(aB[mt], bB[nt], acc[mt][nt], 0, 0, 0);
    }

    // write q (scaled), k, v^T to per-wave LDS.  C layout: col=lane&15, row=lg*4+r
#pragma unroll
    for (int nt = 0; nt < 6; ++nt) {
      float qb = qkv_b[jrow[nt]];
#pragma unroll
      for (int mt = 0; mt < 4; ++mt) {
#pragma unroll
        for (int r = 0; r < 4; ++r) {
          float v = acc[mt][nt][r] + qb;
          int tok = mt * 16 + lg * 4 + r;
          int d = (nt & 1) * 16 + lr;
          if (nt < 2)      Qb[tok * QK_STRIDE + d] = f2bf(v * scale);
          else if (nt < 4) Kb[tok * QK_STRIDE + d] = f2bf(v);
          else             Vt[d * VT_STRIDE + tok] = f2bf(v);
        }
      }
    }
    // per-wave buffers + in-order DS pipe: no barrier needed

    // ---------- phase 2: S = qk^T, softmax, O = P v ----------
    bf16x8 qf[4], kf[4];
#pragma unroll
    for (int t = 0; t < 4; ++t) {
      qf[t] = *(const bf16x8*)&Qb[(t * 16 + lr) * QK_STRIDE + lg * 8];
      kf[t] = *(const bf16x8*)&Kb[(t * 16 + lr) * QK_STRIDE + lg * 8];
    }
    f32x4 S[4][4];
#pragma unroll
    for (int mt = 0; mt < 4; ++mt)
#pragma unroll
      for (int nt = 0; nt < 4; ++nt)
        S[mt][nt] = __builtin_amdgcn_mfma_f32_16x16x32_bf16(qf[mt], kf[nt], fzero, 0, 0, 0);

    const float* bh = bias + h * 2401;
#pragma unroll
    for (int mt = 0; mt < 4; ++mt) {
      // bias + pad mask
#pragma unroll
      for (int nt = 0; nt < 4; ++nt) {
        int m = nt * 16 + lr;
#pragma unroll
        for (int r = 0; r < 4; ++r) {
          int n = mt * 16 + lg * 4 + r;
          float s = S[mt][nt][r];
          S[mt][nt][r] = (m < NW && n < NW) ? s + bh[n * NW + m] : -1e30f;
        }
      }
      // wave-parallel softmax: row = 16 lanes x 4 nt tiles
#pragma unroll
      for (int r = 0; r < 4; ++r) {
        float mx = fmaxf(fmaxf(S[mt][0][r], S[mt][1][r]), fmaxf(S[mt][2][r], S[mt][3][r]));
        mx = fmaxf(mx, __shfl_xor(mx, 1));
        mx = fmaxf(mx, __shfl_xor(mx, 2));
        mx = fmaxf(mx, __shfl_xor(mx, 4));
        mx = fmaxf(mx, __shfl_xor(mx, 8));
        float sum = 0.f;
#pragma unroll
        for (int nt = 0; nt < 4; ++nt) {
          float e = __expf(S[mt][nt][r] - mx);
          S[mt][nt][r] = e; sum += e;
        }
        sum += __shfl_xor(sum, 1);
        sum += __shfl_xor(sum, 2);
        sum += __shfl_xor(sum, 4);
        sum += __shfl_xor(sum, 8);
        float inv = 1.0f / sum;
#pragma unroll
        for (int nt = 0; nt < 4; ++nt) S[mt][nt][r] *= inv;
      }
      // repack P tile [16][64] -> LDS, then PV for this row tile
#pragma unroll
      for (int nt = 0; nt < 4; ++nt)
#pragma unroll
        for (int r = 0; r < 4; ++r)
          Pb[(lg * 4 + r) * P_STRIDE + nt * 16 + lr] = f2bf(S[mt][nt][r]);
      bf16x8 pf0 = *(const bf16x8*)&Pb[lr * P_STRIDE + lg * 8];
      bf16x8 pf1 = *(const bf16x8*)&Pb[lr * P_STRIDE + 32 + lg * 8];
#pragma unroll
      for (int vt = 0; vt < 2; ++vt) {
        bf16x8 v0 = *(const bf16x8*)&Vt[(vt * 16 + lr) * VT_STRIDE + lg * 8];
        bf16x8 v1 = *(const bf16x8*)&Vt[(vt * 16 + lr) * VT_STRIDE + 32 + lg * 8];
        f32x4 o = __builtin_amdgcn_mfma_f32_16x16x32_bf16(pf0, v0, fzero, 0, 0, 0);
        o = __builtin_amdgcn_mfma_f32_16x16x32_bf16(pf1, v1, o, 0, 0, 0);
#pragma unroll
        for (int r = 0; r < 4; ++r)
          ao[(mt * 16 + lg * 4 + r) * XS_STRIDE + h * HDIM + vt * 16 + lr] = f2bf(o[r]);
      }
    }
  }
  __syncthreads();

  // ---------- phase 3: out = ao @ proj_w^T + proj_b (waves split N) ----------
  f32x4 oacc[4][6];
#pragma unroll
  for (int mt = 0; mt < 4; ++mt)
#pragma unroll
    for (int n6 = 0; n6 < 6; ++n6) oacc[mt][n6] = fzero;

  const int jbase = wid * 96;
  bf16x8 aA2[4], bA2[6], aB2[4], bB2[6];
  {
    int k0 = lg * 8;
#pragma unroll
    for (int mt = 0; mt < 4; ++mt) aA2[mt] = *(const bf16x8*)&ao[(mt * 16 + lr) * XS_STRIDE + k0];
#pragma unroll
    for (int n6 = 0; n6 < 6; ++n6) bA2[n6] = *(const bf16x8*)&wp[(jbase + n6 * 16 + lr) * CDIM + k0];
  }
#pragma unroll
  for (int kk = 0; kk < 6; ++kk) {
    {
      int k0 = (2 * kk + 1) * 32 + lg * 8;
#pragma unroll
      for (int mt = 0; mt < 4; ++mt) aB2[mt] = *(const bf16x8*)&ao[(mt * 16 + lr) * XS_STRIDE + k0];
#pragma unroll
      for (int n6 = 0; n6 < 6; ++n6) bB2[n6] = *(const bf16x8*)&wp[(jbase + n6 * 16 + lr) * CDIM + k0];
    }
#pragma unroll
    for (int n6 = 0; n6 < 6; ++n6)
#pragma unroll
      for (int mt = 0; mt < 4; ++mt)
        oacc[mt][n6] = __builtin_amdgcn_mfma_f32_16x16x32_bf16(aA2[mt], bA2[n6], oacc[mt][n6], 0, 0, 0);
    if (kk < 5) {
      int k0 = (2 * kk + 2) * 32 + lg * 8;
#pragma unroll
      for (int mt = 0; mt < 4; ++mt) aA2[mt] = *(const bf16x8*)&ao[(mt * 16 + lr) * XS_STRIDE + k0];
#pragma unroll
      for (int n6 = 0; n6 < 6; ++n6) bA2[n6] = *(const bf16x8*)&wp[(jbase + n6 * 16 + lr) * CDIM + k0];
    }
#pragma unroll
    for (int n6 = 0; n6 < 6; ++n6)
#pragma unroll
      for (int mt = 0; mt < 4; ++mt)
        oacc[mt][n6] = __builtin_amdgcn_mfma_f32_16x16x32_bf16(aB2[mt], bB2[n6], oacc[mt][n6], 0, 0, 0);
  }

  float* ob = out + (size_t)b * (NW * CDIM);
#pragma unroll
  for (int n6 = 0; n6 < 6; ++n6) {
    int j = jbase + n6 * 16 + lr;
    float pbv = proj_b[j];
#pragma unroll
    for (int mt = 0; mt < 4; ++mt)
#pragma unroll
      for (int r = 0; r < 4; ++r) {
        int tok = mt * 16 + lg * 4 + r;
        if (tok < NW) ob[(size_t)tok * CDIM + j] = oacc[mt][n6][r] + pbv;
      }
  }
}

extern "C" void kernel_launch(void* const* d_in, const int* in_sizes, int n_in,
                              void* d_out, int out_size, void* d_ws, size_t ws_size,
                              hipStream_t stream) {
  const float* x      = (const float*)d_in[0];
  const float* qkv_w  = (const float*)d_in[1];
  const float* qkv_b  = (const float*)d_in[2];
  const float* proj_w = (const float*)d_in[3];
  const float* proj_b = (const float*)d_in[4];
  const float* rpb    = (const float*)d_in[5];
  const int*   rel    = (const int*)d_in[6];
  float* out = (float*)d_out;

  u16* wq = (u16*)d_ws;                            // 1152*384 bf16  = 884736 B
  u16* wp = (u16*)((char*)d_ws + 884736);          // 384*384 bf16   = 294912 B
  float* bias = (float*)((char*)d_ws + 1179648);   // 12*49*49 fp32  = 115248 B

  int nB = in_sizes[0] / (NW * CDIM);  // 4096

  prep_kernel<<<dim3((1152 * 384 + 255) / 256), dim3(256), 0, stream>>>(
      qkv_w, proj_w, rpb, rel, wq, wp, bias);

  (void)hipFuncSetAttribute((const void*)wattn_kernel,
                            hipFuncAttributeMaxDynamicSharedMemorySize, LDS_BYTES);
  wattn_kernel<<<dim3(nB), dim3(256), LDS_BYTES, stream>>>(
      x, qkv_b, proj_b, wq, wp, bias, out);
}

// Round 3
// 1465.691 us; speedup vs baseline: 1.0838x; 1.0838x over previous
//
#include <hip/hip_runtime.h>

typedef __attribute__((ext_vector_type(8))) short bf16x8;
typedef __attribute__((ext_vector_type(4))) float f32x4;
typedef unsigned short u16;
typedef unsigned int u32;

#define NW 49
#define NP 64
#define CDIM 384
#define NHEAD 12
#define HDIM 32
#define XS_STRIDE 392   // bf16 elems; 784 B row stride: 16B-aligned, ~2-way banks
#define QK_STRIDE 40    // 80 B row stride
#define VT_STRIDE 72    // 144 B row stride
#define P_STRIDE 72
// kernel A LDS: xs 64*392*2 = 50176 B + 4 waves * 6912 B = 77824 B -> 2 blocks/CU
#define WB_U16 3456
#define LDS_A_BYTES (NP * XS_STRIDE * 2 + 4 * WB_U16 * 2)

__device__ __forceinline__ u16 f2bf(float f) {
  u32 u = __float_as_uint(f);
  u32 r = u + 0x7fffu + ((u >> 16) & 1u);   // RNE
  return (u16)(r >> 16);
}

// prep: weights fp32->bf16, bias[h][n][m] = rpb[rel[n,m]][h]
__global__ void prep_kernel(const float* __restrict__ qkv_w,
                            const float* __restrict__ proj_w,
                            const float* __restrict__ rpb,
                            const int* __restrict__ rel,
                            u16* __restrict__ wq, u16* __restrict__ wp,
                            float* __restrict__ bias) {
  int i = blockIdx.x * 256 + threadIdx.x;
  if (i < 1152 * 384) wq[i] = f2bf(qkv_w[i]);
  if (i < 384 * 384) wp[i] = f2bf(proj_w[i]);
  if (i < 12 * 2401) {
    int h = i / 2401, nm = i % 2401;
    bias[i] = rpb[rel[nm] * 12 + h];
  }
}

// kernel A: fused QKV-proj + window attention; writes pre-proj attn out (fp32) to aout
__global__ __launch_bounds__(256, 2)
void wattn2_kernel(const float* __restrict__ x,
                   const float* __restrict__ qkv_b,
                   const u16* __restrict__ wq,
                   const float* __restrict__ bias,
                   float* __restrict__ aout) {
  extern __shared__ u16 lds[];
  const int b = blockIdx.x;
  const int tid = threadIdx.x;
  const int wid = tid >> 6;
  const int lane = tid & 63;
  const int lr = lane & 15;   // row/col within 16 (MFMA frag)
  const int lg = lane >> 4;   // k-group 0..3

  u16* xs = lds;                           // [64][392] bf16 x tile
  u16* wb = lds + NP * XS_STRIDE + wid * WB_U16;  // per-wave 6912 B
  u16* QK = wb;                            // [64][40]  (Q then K, time-shared)
  u16* Vt = wb;                            // [32][72]  (aliases QK after kf read)
  u16* Pb = wb + 2304;                     // [16][72]

  // ---------- phase 0: stage x -> xs bf16, zero pad rows 49..63 ----------
  const float* xb = x + (size_t)b * (NW * CDIM);
  for (int i = tid; i < 15 * XS_STRIDE; i += 256) xs[49 * XS_STRIDE + i] = 0;
  for (int i = tid; i < 49 * 96; i += 256) {
    int r = i / 96, c4 = i % 96;
    float4 v = ((const float4*)xb)[i];
    ushort4 uu;
    uu.x = f2bf(v.x); uu.y = f2bf(v.y); uu.z = f2bf(v.z); uu.w = f2bf(v.w);
    *(ushort4*)&xs[r * XS_STRIDE + c4 * 4] = uu;
  }
  __syncthreads();

  const f32x4 fzero = {0.f, 0.f, 0.f, 0.f};
  const float scale = 0.17677669529663687f;  // 1/sqrt(32)

  for (int g = 0; g < 3; ++g) {
    const int h = g * 4 + wid;  // this wave's head

    // ---------- phase 1: qkv gemm for head h: M=64 N=96 K=384 ----------
    int jrow[6];
#pragma unroll
    for (int nt = 0; nt < 6; ++nt)
      jrow[nt] = (nt >> 1) * CDIM + h * HDIM + (nt & 1) * 16 + lr;

    f32x4 acc[4][6];
#pragma unroll
    for (int mt = 0; mt < 4; ++mt)
#pragma unroll
      for (int nt = 0; nt < 6; ++nt) acc[mt][nt] = fzero;

    bf16x8 aA[4], bA[6], aB[4], bB[6];
    {
      int k0 = lg * 8;
#pragma unroll
      for (int mt = 0; mt < 4; ++mt) aA[mt] = *(const bf16x8*)&xs[(mt * 16 + lr) * XS_STRIDE + k0];
#pragma unroll
      for (int nt = 0; nt < 6; ++nt) bA[nt] = *(const bf16x8*)&wq[jrow[nt] * CDIM + k0];
    }
#pragma unroll
    for (int kk = 0; kk < 6; ++kk) {
      {  // prefetch kt = 2kk+1
        int k0 = (2 * kk + 1) * 32 + lg * 8;
#pragma unroll
        for (int mt = 0; mt < 4; ++mt) aB[mt] = *(const bf16x8*)&xs[(mt * 16 + lr) * XS_STRIDE + k0];
#pragma unroll
        for (int nt = 0; nt < 6; ++nt) bB[nt] = *(const bf16x8*)&wq[jrow[nt] * CDIM + k0];
      }
      __builtin_amdgcn_s_setprio(1);
#pragma unroll
      for (int nt = 0; nt < 6; ++nt)
#pragma unroll
        for (int mt = 0; mt < 4; ++mt)
          acc[mt][nt] = __builtin_amdgcn_mfma_f32_16x16x32_bf16(aA[mt], bA[nt], acc[mt][nt], 0, 0, 0);
      __builtin_amdgcn_s_setprio(0);
      if (kk < 5) {  // prefetch kt = 2kk+2
        int k0 = (2 * kk + 2) * 32 + lg * 8;
#pragma unroll
        for (int mt = 0; mt < 4; ++mt) aA[mt] = *(const bf16x8*)&xs[(mt * 16 + lr) * XS_STRIDE + k0];
#pragma unroll
        for (int nt = 0; nt < 6; ++nt) bA[nt] = *(const bf16x8*)&wq[jrow[nt] * CDIM + k0];
      }
      __builtin_amdgcn_s_setprio(1);
#pragma unroll
      for (int nt = 0; nt < 6; ++nt)
#pragma unroll
        for (int mt = 0; mt < 4; ++mt)
          acc[mt][nt] = __builtin_amdgcn_mfma_f32_16x16x32_bf16(aB[mt], bB[nt], acc[mt][nt], 0, 0, 0);
      __builtin_amdgcn_s_setprio(0);
    }

    // ---------- repack via time-shared per-wave buffer ----------
    // C layout: col(d)=lr, row(tok)=mt*16+lg*4+r
    // 1) Q (scaled) -> QK, read qf
#pragma unroll
    for (int nt = 0; nt < 2; ++nt) {
      float qb = qkv_b[jrow[nt]];
#pragma unroll
      for (int mt = 0; mt < 4; ++mt)
#pragma unroll
        for (int r = 0; r < 4; ++r) {
          int tok = mt * 16 + lg * 4 + r;
          QK[tok * QK_STRIDE + (nt & 1) * 16 + lr] = f2bf((acc[mt][nt][r] + qb) * scale);
        }
    }
    bf16x8 qf[4], kf[4];
#pragma unroll
    for (int t = 0; t < 4; ++t)
      qf[t] = *(const bf16x8*)&QK[(t * 16 + lr) * QK_STRIDE + lg * 8];
    // 2) K -> QK (overwrites Q; qf already in regs; per-wave DS is in-order)
#pragma unroll
    for (int nt = 2; nt < 4; ++nt) {
      float qb = qkv_b[jrow[nt]];
#pragma unroll
      for (int mt = 0; mt < 4; ++mt)
#pragma unroll
        for (int r = 0; r < 4; ++r) {
          int tok = mt * 16 + lg * 4 + r;
          QK[tok * QK_STRIDE + (nt & 1) * 16 + lr] = f2bf(acc[mt][nt][r] + qb);
        }
    }
#pragma unroll
    for (int t = 0; t < 4; ++t)
      kf[t] = *(const bf16x8*)&QK[(t * 16 + lr) * QK_STRIDE + lg * 8];
    // 3) V^T -> Vt (overwrites QK region; kf already in regs)
#pragma unroll
    for (int nt = 4; nt < 6; ++nt) {
      float qb = qkv_b[jrow[nt]];
#pragma unroll
      for (int mt = 0; mt < 4; ++mt)
#pragma unroll
        for (int r = 0; r < 4; ++r) {
          int tok = mt * 16 + lg * 4 + r;
          int d = (nt & 1) * 16 + lr;
          Vt[d * VT_STRIDE + tok] = f2bf(acc[mt][nt][r] + qb);
        }
    }

    // ---------- phase 2: S = qk^T, softmax, O = P v ----------
    f32x4 S[4][4];
    __builtin_amdgcn_s_setprio(1);
#pragma unroll
    for (int mt = 0; mt < 4; ++mt)
#pragma unroll
      for (int nt = 0; nt < 4; ++nt)
        S[mt][nt] = __builtin_amdgcn_mfma_f32_16x16x32_bf16(qf[mt], kf[nt], fzero, 0, 0, 0);
    __builtin_amdgcn_s_setprio(0);

    const float* bh = bias + h * 2401;
    float* ob = aout + (size_t)b * (NW * CDIM) + h * HDIM;
#pragma unroll
    for (int mt = 0; mt < 4; ++mt) {
      // bias + pad mask
#pragma unroll
      for (int nt = 0; nt < 4; ++nt) {
        int m = nt * 16 + lr;
#pragma unroll
        for (int r = 0; r < 4; ++r) {
          int n = mt * 16 + lg * 4 + r;
          float s = S[mt][nt][r];
          S[mt][nt][r] = (m < NW && n < NW) ? s + bh[n * NW + m] : -1e30f;
        }
      }
      // wave-parallel softmax: row = 16 lanes x 4 nt tiles
#pragma unroll
      for (int r = 0; r < 4; ++r) {
        float mx = fmaxf(fmaxf(S[mt][0][r], S[mt][1][r]), fmaxf(S[mt][2][r], S[mt][3][r]));
        mx = fmaxf(mx, __shfl_xor(mx, 1));
        mx = fmaxf(mx, __shfl_xor(mx, 2));
        mx = fmaxf(mx, __shfl_xor(mx, 4));
        mx = fmaxf(mx, __shfl_xor(mx, 8));
        float sum = 0.f;
#pragma unroll
        for (int nt = 0; nt < 4; ++nt) {
          float e = __expf(S[mt][nt][r] - mx);
          S[mt][nt][r] = e; sum += e;
        }
        sum += __shfl_xor(sum, 1);
        sum += __shfl_xor(sum, 2);
        sum += __shfl_xor(sum, 4);
        sum += __shfl_xor(sum, 8);
        float inv = 1.0f / sum;
#pragma unroll
        for (int nt = 0; nt < 4; ++nt) S[mt][nt][r] *= inv;
      }
      // repack P tile [16][64] -> LDS, then PV for this row tile
#pragma unroll
      for (int nt = 0; nt < 4; ++nt)
#pragma unroll
        for (int r = 0; r < 4; ++r)
          Pb[(lg * 4 + r) * P_STRIDE + nt * 16 + lr] = f2bf(S[mt][nt][r]);
      bf16x8 pf0 = *(const bf16x8*)&Pb[lr * P_STRIDE + lg * 8];
      bf16x8 pf1 = *(const bf16x8*)&Pb[lr * P_STRIDE + 32 + lg * 8];
#pragma unroll
      for (int vt = 0; vt < 2; ++vt) {
        bf16x8 v0 = *(const bf16x8*)&Vt[(vt * 16 + lr) * VT_STRIDE + lg * 8];
        bf16x8 v1 = *(const bf16x8*)&Vt[(vt * 16 + lr) * VT_STRIDE + 32 + lg * 8];
        __builtin_amdgcn_s_setprio(1);
        f32x4 o = __builtin_amdgcn_mfma_f32_16x16x32_bf16(pf0, v0, fzero, 0, 0, 0);
        o = __builtin_amdgcn_mfma_f32_16x16x32_bf16(pf1, v1, o, 0, 0, 0);
        __builtin_amdgcn_s_setprio(0);
#pragma unroll
        for (int r = 0; r < 4; ++r) {
          int tok = mt * 16 + lg * 4 + r;
          if (tok < NW) ob[(size_t)tok * CDIM + vt * 16 + lr] = o[r];
        }
      }
    }
  }
}

// kernel B: io[m0..m0+64) = bf16(io rows) @ wp^T + proj_b  (rows block-private)
__global__ __launch_bounds__(256, 2)
void proj_kernel(const u16* __restrict__ wp,
                 const float* __restrict__ proj_b,
                 float* __restrict__ io) {
  __shared__ u16 As[NP * XS_STRIDE];
  const int tid = threadIdx.x;
  const int wid = tid >> 6;
  const int lane = tid & 63;
  const int lr = lane & 15;
  const int lg = lane >> 4;
  const int m0 = blockIdx.x * 64;

  // stage 64 rows of io -> As as bf16 (read BEFORE any write; rows private to block)
  const float* src = io + (size_t)m0 * CDIM;
  for (int i = tid; i < 64 * 96; i += 256) {
    int r = i / 96, c4 = i % 96;
    float4 v = ((const float4*)src)[i];
    ushort4 uu;
    uu.x = f2bf(v.x); uu.y = f2bf(v.y); uu.z = f2bf(v.z); uu.w = f2bf(v.w);
    *(ushort4*)&As[r * XS_STRIDE + c4 * 4] = uu;
  }
  __syncthreads();

  const f32x4 fzero = {0.f, 0.f, 0.f, 0.f};
  f32x4 oacc[4][6];
#pragma unroll
  for (int mt = 0; mt < 4; ++mt)
#pragma unroll
    for (int n6 = 0; n6 < 6; ++n6) oacc[mt][n6] = fzero;

  const int jbase = wid * 96;
  bf16x8 aA2[4], bA2[6], aB2[4], bB2[6];
  {
    int k0 = lg * 8;
#pragma unroll
    for (int mt = 0; mt < 4; ++mt) aA2[mt] = *(const bf16x8*)&As[(mt * 16 + lr) * XS_STRIDE + k0];
#pragma unroll
    for (int n6 = 0; n6 < 6; ++n6) bA2[n6] = *(const bf16x8*)&wp[(jbase + n6 * 16 + lr) * CDIM + k0];
  }
#pragma unroll
  for (int kk = 0; kk < 6; ++kk) {
    {
      int k0 = (2 * kk + 1) * 32 + lg * 8;
#pragma unroll
      for (int mt = 0; mt < 4; ++mt) aB2[mt] = *(const bf16x8*)&As[(mt * 16 + lr) * XS_STRIDE + k0];
#pragma unroll
      for (int n6 = 0; n6 < 6; ++n6) bB2[n6] = *(const bf16x8*)&wp[(jbase + n6 * 16 + lr) * CDIM + k0];
    }
    __builtin_amdgcn_s_setprio(1);
#pragma unroll
    for (int n6 = 0; n6 < 6; ++n6)
#pragma unroll
      for (int mt = 0; mt < 4; ++mt)
        oacc[mt][n6] = __builtin_amdgcn_mfma_f32_16x16x32_bf16(aA2[mt], bA2[n6], oacc[mt][n6], 0, 0, 0);
    __builtin_amdgcn_s_setprio(0);
    if (kk < 5) {
      int k0 = (2 * kk + 2) * 32 + lg * 8;
#pragma unroll
      for (int mt = 0; mt < 4; ++mt) aA2[mt] = *(const bf16x8*)&As[(mt * 16 + lr) * XS_STRIDE + k0];
#pragma unroll
      for (int n6 = 0; n6 < 6; ++n6) bA2[n6] = *(const bf16x8*)&wp[(jbase + n6 * 16 + lr) * CDIM + k0];
    }
    __builtin_amdgcn_s_setprio(1);
#pragma unroll
    for (int n6 = 0; n6 < 6; ++n6)
#pragma unroll
      for (int mt = 0; mt < 4; ++mt)
        oacc[mt][n6] = __builtin_amdgcn_mfma_f32_16x16x32_bf16(aB2[mt], bB2[n6], oacc[mt][n6], 0, 0, 0);
    __builtin_amdgcn_s_setprio(0);
  }

  float* ob = io + (size_t)m0 * CDIM;
#pragma unroll
  for (int n6 = 0; n6 < 6; ++n6) {
    int j = jbase + n6 * 16 + lr;
    float pbv = proj_b[j];
#pragma unroll
    for (int mt = 0; mt < 4; ++mt)
#pragma unroll
      for (int r = 0; r < 4; ++r) {
        int tok = mt * 16 + lg * 4 + r;
        ob[(size_t)tok * CDIM + j] = oacc[mt][n6][r] + pbv;
      }
  }
}

extern "C" void kernel_launch(void* const* d_in, const int* in_sizes, int n_in,
                              void* d_out, int out_size, void* d_ws, size_t ws_size,
                              hipStream_t stream) {
  const float* x      = (const float*)d_in[0];
  const float* qkv_w  = (const float*)d_in[1];
  const float* qkv_b  = (const float*)d_in[2];
  const float* proj_w = (const float*)d_in[3];
  const float* proj_b = (const float*)d_in[4];
  const float* rpb    = (const float*)d_in[5];
  const int*   rel    = (const int*)d_in[6];
  float* out = (float*)d_out;

  u16* wq = (u16*)d_ws;                            // 1152*384 bf16  = 884736 B
  u16* wp = (u16*)((char*)d_ws + 884736);          // 384*384 bf16   = 294912 B
  float* bias = (float*)((char*)d_ws + 1179648);   // 12*49*49 fp32  = 115248 B

  int nB = in_sizes[0] / (NW * CDIM);      // 4096 windows
  int nRows = in_sizes[0] / CDIM;          // 200704 rows
  int nB2 = nRows / 64;                    // 3136 proj blocks

  prep_kernel<<<dim3((1152 * 384 + 255) / 256), dim3(256), 0, stream>>>(
      qkv_w, proj_w, rpb, rel, wq, wp, bias);

  (void)hipFuncSetAttribute((const void*)wattn2_kernel,
                            hipFuncAttributeMaxDynamicSharedMemorySize, LDS_A_BYTES);
  wattn2_kernel<<<dim3(nB), dim3(256), LDS_A_BYTES, stream>>>(
      x, qkv_b, wq, bias, out);

  proj_kernel<<<dim3(nB2), dim3(256), 0, stream>>>(wp, proj_b, out);
}